// Round 14
// baseline (254.361 us; speedup 1.0000x reference)
//
#include <hip/hip_runtime.h>
#include <stdint.h>

#define NSITE 512
#define DD    64
#define NB    64
#define NO    10
#define NSEG  16
#define SEGLEN 32
#define SLAB_BYTES 32768   // fp32 site slab stride
#define PACK_BYTES 16384   // packed bf16 Wstk image (front half of slab)

typedef short bf16x8 __attribute__((ext_vector_type(8)));
typedef float f32x16 __attribute__((ext_vector_type(16)));

// trunc-pack two f32 -> packed bf16 dword (lo=a, hi=b) in ONE v_perm_b32
__device__ __forceinline__ uint32_t pk2(float a, float b) {
    return __builtin_amdgcn_perm(__float_as_uint(b), __float_as_uint(a), 0x07060302);
}

// packed f32 pair multiply: one VOP3P instruction
__device__ __forceinline__ float2 pkmul2(float2 a, float2 b) {
    float2 r;
    asm("v_pk_mul_f32 %0, %1, %2" : "=v"(r) : "v"(a), "v"(b));
    return r;
}

__device__ __forceinline__ void dma16(const void* gp, void* lp) {
    __builtin_amdgcn_global_load_lds(
        (const __attribute__((address_space(1))) uint32_t*)gp,
        (__attribute__((address_space(3))) uint32_t*)lp, 16, 0, 0);
}

// ---------------------------------------------------------------------------
// FUSED pack + stage1.  Counter evidence (r13): ~90us residual >> modeled
// pack(~11)+tail(~5) => ~20-25us per-launch overhead dominates.  Fusing pack
// into stage1 kills one launch.  pack->stage1 needs only a GROUP-local
// barrier: the 16 blocks of a (side,seg) group consume only their own 32
// slabs.  Each block packs 2 slabs (proven pack body, in-place), then a
// 16-arrival atomic barrier on d_ws, then the UNCHANGED r13 stage1 body
// (4-slot ring, vmcnt(8)+s_barrier cadence, bfa pre-extract, chained acc,
// XCD swizzle).  Deadlock-free without co-residency: groups are disjoint in
// blocks AND data; any fully-dispatched group progresses; finished groups
// free CUs.  No block ever touches another group's slabs -> no stale cache
// lines on any XCD.  __threadfence() release + device-scope atomics give
// cross-block visibility even if the XCD-grouping heuristic is wrong.
// ---------------------------------------------------------------------------
__global__ __launch_bounds__(256, 2) void stage1_kernel(
        const float* __restrict__ x, float* __restrict__ wl, float* __restrict__ wr,
        int* grpcnt) {
    const int pb   = blockIdx.x;          // physical 0..511
    const int bid  = (pb & 7) * 64 + (pb >> 3);   // logical, XCD-grouped
    const int side = bid >> 8;
    const int seg  = (bid >> 4) & 15;
    const int bq   = bid & 15;
    const int wave = threadIdx.x >> 6;
    const int lane = threadIdx.x & 63;
    const int b    = bq * 4 + wave;
    const int m5   = lane & 31;
    const int H    = lane >> 5;

    __shared__ __align__(16) char ring[4][PACK_BYTES];   // 64 KB
    __shared__ float2 xs[4][SEGLEN];

    char* wbuf = (char*)(side ? wr : wl);

    // ================= phase P: pack this group's 2 slabs =================
    {
        float2* st = (float2*)ring;                  // 33,280 B <= 65,536 B
        #pragma unroll
        for (int rep = 0; rep < 2; ++rep) {
            const int s = seg * SEGLEN + 2 * bq + rep;       // own slab
            float* base = (float*)wbuf + (size_t)s * (SLAB_BYTES / 4);
            const float4* src4 = (const float4*)base;
            for (int e4 = threadIdx.x; e4 < DD * DD / 2; e4 += 256) {
                const float4 v = src4[e4];
                const int e = e4 * 2;
                float2* d = &st[(e >> 6) * 65 + (e & 63)];
                d[0] = make_float2(v.x, v.y);
                d[1] = make_float2(v.z, v.w);
            }
            __syncthreads();
            uint32_t* outp = (uint32_t*)base;        // front 16 KB, in place
            #pragma unroll
            for (int rr = 0; rr < 16; ++rr) {
                const int od = rr * 256 + threadIdx.x;
                const int chunk = od >> 8, i2 = chunk >> 3, sk = chunk & 7;
                const int Hh = (od >> 7) & 1, mm5 = (od >> 2) & 31, dd = od & 3;
                const int m = 32 * i2 + mm5, k = 8 * sk + 4 * Hh + dd;
                const float2 a = side ? st[m * 65 + k] : st[k * 65 + m];
                outp[od] = pk2(a.x, a.y);
            }
            __syncthreads();                          // st reuse / exit
        }
        // ---- group barrier: 16 blocks of (side,seg) ----
        __threadfence();                              // release pack stores
        __syncthreads();                              // all threads fenced
        if (threadIdx.x == 0) {
            const int g = bid >> 4;                   // 0..31
            atomicAdd(&grpcnt[g], 1);
            while (atomicAdd(&grpcnt[g], 0) < 16) { } // device-scope spin
        }
        __syncthreads();
        __threadfence();                              // acquire
    }

    // ================= phase S1: unchanged r13 stage1 =====================
    if (lane < SEGLEN) {
        const float2* xp = ((const float2*)x) + (size_t)b * 1024 + (side ? NSITE : 0);
        const int sg = seg * SEGLEN + (side ? SEGLEN - 1 - lane : lane);
        xs[wave][lane] = xp[sg];
    }

    auto siteAddr = [&](int t) -> const char* {
        const int sg = seg * SEGLEN + (side ? SEGLEN - 1 - t : t);
        return wbuf + (size_t)sg * SLAB_BYTES;
    };

    #pragma unroll
    for (int t0 = 0; t0 < 2; ++t0) {
        const char* sb = siteAddr(t0);
        #pragma unroll
        for (int c = 0; c < 4; ++c) {
            const int ch = wave * 4 + c;
            dma16(sb + ch * 1024 + lane * 16, ring[t0] + ch * 1024);
        }
    }

    // acc := Identity (C/D layout: row=(q&3)+8(q>>2)+4H, col=32j+m5)
    f32x16 acc[2][2];
    #pragma unroll
    for (int i = 0; i < 2; ++i)
        #pragma unroll
        for (int j = 0; j < 2; ++j)
            #pragma unroll
            for (int q = 0; q < 16; ++q) {
                const int row = (q & 3) + 8 * (q >> 2) + 4 * H;
                acc[i][j][q] = (i == j && row == m5) ? 1.f : 0.f;
            }

    // persistent zero C-operand
    f32x16 zf;
    #pragma unroll
    for (int q = 0; q < 16; ++q) zf[q] = 0.f;

    union BU { bf16x8 v; uint32_t w[4]; };

    for (int t = 0; t < SEGLEN; ++t) {
        int t2 = t + 2; if (t2 > SEGLEN - 1) t2 = SEGLEN - 1;   // clamped dummy keeps cadence
        {
            const char* sb = siteAddr(t2);
            char* lb = ring[(t + 2) & 3];
            #pragma unroll
            for (int c = 0; c < 4; ++c) {
                const int ch = wave * 4 + c;
                dma16(sb + ch * 1024 + lane * 16, lb + ch * 1024);
            }
        }
        asm volatile("s_waitcnt vmcnt(8)" ::: "memory");
        asm volatile("s_barrier" ::: "memory");

        const char* rb = ring[t & 3];
        const float2 xv = xs[wave][t];
        const float2 xx = make_float2(xv.x, xv.x);
        const float2 xy = make_float2(xv.y, xv.y);

        // pre-extract ALL B-fragments from acc (reads precede writes; SSA)
        BU bfa[8][2];                              // 64 dwords, static-indexed
        #pragma unroll
        for (int sk = 0; sk < 8; ++sk) {
            const int mi = sk >> 2, qb = 4 * (sk & 3);
            #pragma unroll
            for (int j = 0; j < 2; ++j)
                #pragma unroll
                for (int dp = 0; dp < 2; ++dp) {
                    const float2 v01 = make_float2(acc[mi][j][qb + 2 * dp],
                                                   acc[mi][j][qb + 2 * dp + 1]);
                    const float2 pa = pkmul2(xx, v01);   // {x0*v0, x0*v1}
                    const float2 pb = pkmul2(xy, v01);   // {x1*v0, x1*v1}
                    bfa[sk][j].w[2 * dp + 0] = pk2(pa.x, pb.x);  // kap even: x0
                    bfa[sk][j].w[2 * dp + 1] = pk2(pa.y, pb.y);  // kap odd : x1
                }
        }

        // MFMA cluster: chain directly into acc, C=zf at sk==0
        __builtin_amdgcn_s_setprio(1);
        #pragma unroll
        for (int sk = 0; sk < 8; ++sk) {
            #pragma unroll
            for (int i = 0; i < 2; ++i) {
                union { bf16x8 v; uint4 u; } a;
                a.u = *(const uint4*)(rb + (i * 8 + sk) * 1024 + lane * 16);
                #pragma unroll
                for (int j = 0; j < 2; ++j)
                    acc[i][j] = __builtin_amdgcn_mfma_f32_32x32x16_bf16(
                        a.v, bfa[sk][j].v, (sk == 0) ? zf : acc[i][j], 0, 0, 0);
            }
        }
        __builtin_amdgcn_s_setprio(0);
    }

    // write P (final T, bf16, uint16 index c*64+r) into slab back-halves
    {
        const int p = b * NSEG + seg;                    // 0..1023 per side
        char* pdst = wbuf + (size_t)(p >> 1) * SLAB_BYTES + PACK_BYTES + (p & 1) * 8192;
        #pragma unroll
        for (int i = 0; i < 2; ++i)
            #pragma unroll
            for (int j = 0; j < 2; ++j) {
                const int c = 32 * j + m5;
                #pragma unroll
                for (int Q = 0; Q < 4; ++Q) {
                    const int r0 = 32 * i + 8 * Q + 4 * H;
                    uint2 val;
                    val.x = pk2(acc[i][j][4 * Q + 0], acc[i][j][4 * Q + 1]);
                    val.y = pk2(acc[i][j][4 * Q + 2], acc[i][j][4 * Q + 3]);
                    *(uint2*)(pdst + c * 128 + r0 * 2) = val;
                }
            }
    }
    asm volatile("s_waitcnt vmcnt(0)" ::: "memory");   // drain DMA before endpgm
}

// ---------------------------------------------------------------------------
// FUSED stage2+finalize (unchanged from r13, measured-good): 64 blocks x 512.
// Waves 0-3 fold LEFT, 4-7 fold RIGHT in parallel; P-prefetch + lgkm-only
// raw barriers; o-parallel contraction at the end.
// ---------------------------------------------------------------------------
__global__ __launch_bounds__(512) void tail_kernel(
        const float* __restrict__ wl, const float* __restrict__ wr,
        const float* __restrict__ core, float* __restrict__ out) {
    const int b    = blockIdx.x;         // 0..63
    const int tid  = threadIdx.x;        // 0..511
    const int side = tid >> 8;           // waves 0-3: left, 4-7: right
    const int r    = tid & 63;
    const int cg   = (tid >> 6) & 3;
    const char* wbuf = (const char*)(side ? wr : wl);

    __shared__ float vsh[2][DD];
    __shared__ float part[2][4][DD];
    if ((tid & 255) < DD) vsh[side][r] = (r == 0) ? 1.f : 0.f;

    auto Pseg = [&](int gi) -> const uint16_t* {
        const int g = side ? (NSEG - 1 - gi) : gi;
        const int p = b * NSEG + g;
        return (const uint16_t*)(wbuf
            + (size_t)(p >> 1) * SLAB_BYTES + PACK_BYTES + (p & 1) * 8192);
    };

    float pv[16];
    {
        const uint16_t* P = Pseg(0);
        #pragma unroll
        for (int cc = 0; cc < 16; ++cc)
            pv[cc] = __uint_as_float(((uint32_t)P[(cg * 16 + cc) * 64 + r]) << 16);
    }
    __syncthreads();

    for (int gi = 0; gi < NSEG; ++gi) {
        float nv[16];
        const bool more = (gi + 1 < NSEG);
        if (more) {
            const uint16_t* Pn = Pseg(gi + 1);          // issue early; waited at copy
            #pragma unroll
            for (int cc = 0; cc < 16; ++cc)
                nv[cc] = __uint_as_float(((uint32_t)Pn[(cg * 16 + cc) * 64 + r]) << 16);
        }
        float acc = 0.f;
        #pragma unroll
        for (int cc = 0; cc < 16; ++cc)
            acc = fmaf(vsh[side][cg * 16 + cc], pv[cc], acc);
        part[side][cg][r] = acc;
        asm volatile("s_waitcnt lgkmcnt(0)" ::: "memory");
        __builtin_amdgcn_s_barrier();
        if ((tid & 255) < DD)
            vsh[side][r] = part[side][0][r] + part[side][1][r]
                         + part[side][2][r] + part[side][3][r];
        asm volatile("s_waitcnt lgkmcnt(0)" ::: "memory");
        __builtin_amdgcn_s_barrier();
        if (more) {
            #pragma unroll
            for (int cc = 0; cc < 16; ++cc) pv[cc] = nv[cc];
        }
    }
    // vsh[0] = vL, vsh[1] = wR.  o-parallel contraction across 8 waves.
    const int wv   = tid >> 6;           // 0..7
    const int lane = tid & 63;
    const float wrv = vsh[1][lane];
    for (int o = wv; o < NO; o += 8) {
        float acc = 0.f;
        #pragma unroll 8
        for (int l = 0; l < DD; ++l)
            acc += vsh[0][l] * core[(o * DD + l) * DD + lane];
        acc *= wrv;
        #pragma unroll
        for (int off = 32; off > 0; off >>= 1)
            acc += __shfl_xor(acc, off, 64);
        if (lane == 0) out[b * NO + o] = acc;
    }
}

extern "C" void kernel_launch(void* const* d_in, const int* in_sizes, int n_in,
                              void* d_out, int out_size, void* d_ws, size_t ws_size,
                              hipStream_t stream) {
    const float* x    = (const float*)d_in[0];   // [64][1024][2]
    float*       wl   = (float*)d_in[1];         // [512][64][64][2] -> packed + P scratch
    const float* core = (const float*)d_in[2];   // [10][64][64]
    float*       wr   = (float*)d_in[3];         // [512][64][64][2] -> packed + P scratch
    int* grpcnt = (int*)d_ws;                    // 32 group-barrier counters

    hipMemsetAsync(grpcnt, 0, 32 * sizeof(int), stream);
    stage1_kernel<<<512, 256, 0, stream>>>(x, wl, wr, grpcnt);
    tail_kernel<<<NB, 512, 0, stream>>>(wl, wr, core, (float*)d_out);
}

// Round 15
// 237.036 us; speedup vs baseline: 1.0731x; 1.0731x over previous
//
#include <hip/hip_runtime.h>
#include <stdint.h>

#define NSITE 512
#define DD    64
#define NB    64
#define NO    10
#define NSEG  16
#define SEGLEN 32
#define SLAB_BYTES 32768   // site slab stride (image front 16 KB + P back 16 KB)
#define PACK_BYTES 16384
#define CNT_STRIDE 64      // ints: 256 B between group counters (no line sharing)

typedef short bf16x8 __attribute__((ext_vector_type(8)));
typedef float f32x16 __attribute__((ext_vector_type(16)));

__device__ __forceinline__ uint32_t pk2(float a, float b) {
    return __builtin_amdgcn_perm(__float_as_uint(b), __float_as_uint(a), 0x07060302);
}
__device__ __forceinline__ float2 pkmul2(float2 a, float2 b) {
    float2 r;
    asm("v_pk_mul_f32 %0, %1, %2" : "=v"(r) : "v"(a), "v"(b));
    return r;
}
__device__ __forceinline__ void dma16(const void* gp, void* lp) {
    __builtin_amdgcn_global_load_lds(
        (const __attribute__((address_space(1))) uint32_t*)gp,
        (__attribute__((address_space(3))) uint32_t*)lp, 16, 0, 0);
}

// ---------------------------------------------------------------------------
// FUSED pack + stage1.  r14 validated the fusion (residual -19us) but the
// barrier spin was catastrophic: atomicAdd(p,0) RMW polling with all 32
// counters in ONE cache line (stage1 76->183us).  Fixed: 256B-strided
// counters, poll = plain agent-scope LOAD (no RMW) + s_sleep backoff.
// Arrival/visibility protocol unchanged (threadfence release + device-scope
// add; acquire fence after) -- r14 measured absmax 0.0 with it.
// W srcs (fp32) are READ-ONLY; images+P go to dst slabs (d_ws when large
// enough, else in-place) -- avoids the harness re-poison of 32MB inputs.
// Stage1 body = r13's proven form (4-slot ring, vmcnt(8)+s_barrier, bfa
// pre-extract, chained acc, XCD-group swizzle).
// ---------------------------------------------------------------------------
__global__ __launch_bounds__(256, 2) void stage1_kernel(
        const float* __restrict__ x,
        const float* __restrict__ wlsrc, const float* __restrict__ wrsrc,
        char* __restrict__ dl, char* __restrict__ dr, int* grpcnt) {
    const int pb   = blockIdx.x;          // physical 0..511
    const int bid  = (pb & 7) * 64 + (pb >> 3);   // logical, XCD-grouped
    const int side = bid >> 8;
    const int seg  = (bid >> 4) & 15;
    const int bq   = bid & 15;
    const int wave = threadIdx.x >> 6;
    const int lane = threadIdx.x & 63;
    const int b    = bq * 4 + wave;
    const int m5   = lane & 31;
    const int H    = lane >> 5;

    __shared__ __align__(16) char ring[4][PACK_BYTES];   // 64 KB
    __shared__ float2 xs[4][SEGLEN];

    const float* wsrc = side ? wrsrc : wlsrc;   // fp32 inputs, read-only
    char* wbuf = side ? dr : dl;                // packed image + P scratch

    // ================= phase P: pack this block's 2 slabs =================
    {
        float2* st = (float2*)ring;                  // 33,280 B <= 65,536 B
        #pragma unroll
        for (int rep = 0; rep < 2; ++rep) {
            const int s = seg * SEGLEN + 2 * bq + rep;       // own slab
            const float4* src4 = (const float4*)(wsrc + (size_t)s * (SLAB_BYTES / 4));
            for (int e4 = threadIdx.x; e4 < DD * DD / 2; e4 += 256) {
                const float4 v = src4[e4];
                const int e = e4 * 2;
                float2* d = &st[(e >> 6) * 65 + (e & 63)];
                d[0] = make_float2(v.x, v.y);
                d[1] = make_float2(v.z, v.w);
            }
            __syncthreads();
            uint32_t* outp = (uint32_t*)(wbuf + (size_t)s * SLAB_BYTES);
            #pragma unroll
            for (int rr = 0; rr < 16; ++rr) {
                const int od = rr * 256 + threadIdx.x;
                const int chunk = od >> 8, i2 = chunk >> 3, sk = chunk & 7;
                const int Hh = (od >> 7) & 1, mm5 = (od >> 2) & 31, dd = od & 3;
                const int m = 32 * i2 + mm5, k = 8 * sk + 4 * Hh + dd;
                const float2 a = side ? st[m * 65 + k] : st[k * 65 + m];
                outp[od] = pk2(a.x, a.y);
            }
            __syncthreads();                          // st reuse / exit
        }
        // ---- group barrier: 16 blocks of (side,seg); load-poll, no RMW ----
        __threadfence();                              // release pack stores
        __syncthreads();
        if (threadIdx.x == 0) {
            int* cnt = &grpcnt[(bid >> 4) * CNT_STRIDE];
            atomicAdd(cnt, 1);                        // device-scope arrival
            while (__hip_atomic_load(cnt, __ATOMIC_RELAXED,
                                     __HIP_MEMORY_SCOPE_AGENT) < 16)
                __builtin_amdgcn_s_sleep(2);
        }
        __syncthreads();
        __threadfence();                              // acquire
    }

    // ================= phase S1: proven r13 stage1 ========================
    if (lane < SEGLEN) {
        const float2* xp = ((const float2*)x) + (size_t)b * 1024 + (side ? NSITE : 0);
        const int sg = seg * SEGLEN + (side ? SEGLEN - 1 - lane : lane);
        xs[wave][lane] = xp[sg];
    }

    auto siteAddr = [&](int t) -> const char* {
        const int sg = seg * SEGLEN + (side ? SEGLEN - 1 - t : t);
        return wbuf + (size_t)sg * SLAB_BYTES;
    };

    #pragma unroll
    for (int t0 = 0; t0 < 2; ++t0) {
        const char* sb = siteAddr(t0);
        #pragma unroll
        for (int c = 0; c < 4; ++c) {
            const int ch = wave * 4 + c;
            dma16(sb + ch * 1024 + lane * 16, ring[t0] + ch * 1024);
        }
    }

    f32x16 acc[2][2];
    #pragma unroll
    for (int i = 0; i < 2; ++i)
        #pragma unroll
        for (int j = 0; j < 2; ++j)
            #pragma unroll
            for (int q = 0; q < 16; ++q) {
                const int row = (q & 3) + 8 * (q >> 2) + 4 * H;
                acc[i][j][q] = (i == j && row == m5) ? 1.f : 0.f;
            }

    f32x16 zf;
    #pragma unroll
    for (int q = 0; q < 16; ++q) zf[q] = 0.f;

    union BU { bf16x8 v; uint32_t w[4]; };

    for (int t = 0; t < SEGLEN; ++t) {
        int t2 = t + 2; if (t2 > SEGLEN - 1) t2 = SEGLEN - 1;
        {
            const char* sb = siteAddr(t2);
            char* lb = ring[(t + 2) & 3];
            #pragma unroll
            for (int c = 0; c < 4; ++c) {
                const int ch = wave * 4 + c;
                dma16(sb + ch * 1024 + lane * 16, lb + ch * 1024);
            }
        }
        asm volatile("s_waitcnt vmcnt(8)" ::: "memory");
        asm volatile("s_barrier" ::: "memory");

        const char* rb = ring[t & 3];
        const float2 xv = xs[wave][t];
        const float2 xx = make_float2(xv.x, xv.x);
        const float2 xy = make_float2(xv.y, xv.y);

        BU bfa[8][2];
        #pragma unroll
        for (int sk = 0; sk < 8; ++sk) {
            const int mi = sk >> 2, qb = 4 * (sk & 3);
            #pragma unroll
            for (int j = 0; j < 2; ++j)
                #pragma unroll
                for (int dp = 0; dp < 2; ++dp) {
                    const float2 v01 = make_float2(acc[mi][j][qb + 2 * dp],
                                                   acc[mi][j][qb + 2 * dp + 1]);
                    const float2 pa = pkmul2(xx, v01);
                    const float2 pb = pkmul2(xy, v01);
                    bfa[sk][j].w[2 * dp + 0] = pk2(pa.x, pb.x);
                    bfa[sk][j].w[2 * dp + 1] = pk2(pa.y, pb.y);
                }
        }

        __builtin_amdgcn_s_setprio(1);
        #pragma unroll
        for (int sk = 0; sk < 8; ++sk) {
            #pragma unroll
            for (int i = 0; i < 2; ++i) {
                union { bf16x8 v; uint4 u; } a;
                a.u = *(const uint4*)(rb + (i * 8 + sk) * 1024 + lane * 16);
                #pragma unroll
                for (int j = 0; j < 2; ++j)
                    acc[i][j] = __builtin_amdgcn_mfma_f32_32x32x16_bf16(
                        a.v, bfa[sk][j].v, (sk == 0) ? zf : acc[i][j], 0, 0, 0);
            }
        }
        __builtin_amdgcn_s_setprio(0);
    }

    {
        const int p = b * NSEG + seg;
        char* pdst = wbuf + (size_t)(p >> 1) * SLAB_BYTES + PACK_BYTES + (p & 1) * 8192;
        #pragma unroll
        for (int i = 0; i < 2; ++i)
            #pragma unroll
            for (int j = 0; j < 2; ++j) {
                const int c = 32 * j + m5;
                #pragma unroll
                for (int Q = 0; Q < 4; ++Q) {
                    const int r0 = 32 * i + 8 * Q + 4 * H;
                    uint2 val;
                    val.x = pk2(acc[i][j][4 * Q + 0], acc[i][j][4 * Q + 1]);
                    val.y = pk2(acc[i][j][4 * Q + 2], acc[i][j][4 * Q + 3]);
                    *(uint2*)(pdst + c * 128 + r0 * 2) = val;
                }
            }
    }
    asm volatile("s_waitcnt vmcnt(0)" ::: "memory");
}

// ---------------------------------------------------------------------------
// FUSED stage2+finalize (r13, measured-good): 64 blocks x 512 threads.
// ---------------------------------------------------------------------------
__global__ __launch_bounds__(512) void tail_kernel(
        const char* __restrict__ dl, const char* __restrict__ dr,
        const float* __restrict__ core, float* __restrict__ out) {
    const int b    = blockIdx.x;
    const int tid  = threadIdx.x;
    const int side = tid >> 8;
    const int r    = tid & 63;
    const int cg   = (tid >> 6) & 3;
    const char* wbuf = side ? dr : dl;

    __shared__ float vsh[2][DD];
    __shared__ float part[2][4][DD];
    if ((tid & 255) < DD) vsh[side][r] = (r == 0) ? 1.f : 0.f;

    auto Pseg = [&](int gi) -> const uint16_t* {
        const int g = side ? (NSEG - 1 - gi) : gi;
        const int p = b * NSEG + g;
        return (const uint16_t*)(wbuf
            + (size_t)(p >> 1) * SLAB_BYTES + PACK_BYTES + (p & 1) * 8192);
    };

    float pv[16];
    {
        const uint16_t* P = Pseg(0);
        #pragma unroll
        for (int cc = 0; cc < 16; ++cc)
            pv[cc] = __uint_as_float(((uint32_t)P[(cg * 16 + cc) * 64 + r]) << 16);
    }
    __syncthreads();

    for (int gi = 0; gi < NSEG; ++gi) {
        float nv[16];
        const bool more = (gi + 1 < NSEG);
        if (more) {
            const uint16_t* Pn = Pseg(gi + 1);
            #pragma unroll
            for (int cc = 0; cc < 16; ++cc)
                nv[cc] = __uint_as_float(((uint32_t)Pn[(cg * 16 + cc) * 64 + r]) << 16);
        }
        float acc = 0.f;
        #pragma unroll
        for (int cc = 0; cc < 16; ++cc)
            acc = fmaf(vsh[side][cg * 16 + cc], pv[cc], acc);
        part[side][cg][r] = acc;
        asm volatile("s_waitcnt lgkmcnt(0)" ::: "memory");
        __builtin_amdgcn_s_barrier();
        if ((tid & 255) < DD)
            vsh[side][r] = part[side][0][r] + part[side][1][r]
                         + part[side][2][r] + part[side][3][r];
        asm volatile("s_waitcnt lgkmcnt(0)" ::: "memory");
        __builtin_amdgcn_s_barrier();
        if (more) {
            #pragma unroll
            for (int cc = 0; cc < 16; ++cc) pv[cc] = nv[cc];
        }
    }
    const int wv   = tid >> 6;
    const int lane = tid & 63;
    const float wrv = vsh[1][lane];
    for (int o = wv; o < NO; o += 8) {
        float acc = 0.f;
        #pragma unroll 8
        for (int l = 0; l < DD; ++l)
            acc += vsh[0][l] * core[(o * DD + l) * DD + lane];
        acc *= wrv;
        #pragma unroll
        for (int off = 32; off > 0; off >>= 1)
            acc += __shfl_xor(acc, off, 64);
        if (lane == 0) out[b * NO + o] = acc;
    }
}

extern "C" void kernel_launch(void* const* d_in, const int* in_sizes, int n_in,
                              void* d_out, int out_size, void* d_ws, size_t ws_size,
                              hipStream_t stream) {
    const float* x    = (const float*)d_in[0];   // [64][1024][2]
    float*       wl   = (float*)d_in[1];         // [512][64][64][2] fp32 (read-only if ws fits)
    const float* core = (const float*)d_in[2];   // [10][64][64]
    float*       wr   = (float*)d_in[3];

    const size_t cntBytes = 32 * CNT_STRIDE * sizeof(int);          // 8 KB
    const size_t need = cntBytes + 2 * (size_t)NSITE * SLAB_BYTES;  // 8 KB + 32 MB
    int*  grpcnt = (int*)d_ws;
    char* dl;
    char* dr;
    if (ws_size >= need) {           // keep inputs pristine (no harness re-poison)
        dl = (char*)d_ws + cntBytes;
        dr = dl + (size_t)NSITE * SLAB_BYTES;
    } else {                          // fallback: in-place (r14 behavior)
        dl = (char*)wl;
        dr = (char*)wr;
    }

    hipMemsetAsync(grpcnt, 0, cntBytes, stream);
    stage1_kernel<<<512, 256, 0, stream>>>(x, wl, wr, dl, dr, grpcnt);
    tail_kernel<<<NB, 512, 0, stream>>>(dl, dr, core, (float*)d_out);
}

// Round 19
// 235.600 us; speedup vs baseline: 1.0796x; 1.0061x over previous
//
#include <hip/hip_runtime.h>
#include <stdint.h>

#define NSITE 512
#define DD    64
#define NB    64
#define NO    10
#define NSEG  16
#define SEGLEN 32
#define SLAB_BYTES 32768   // fp32 site slab stride
#define PACK_BYTES 16384   // packed bf16 Wstk image (front half of slab)

typedef short bf16x8 __attribute__((ext_vector_type(8)));
typedef float f32x16 __attribute__((ext_vector_type(16)));

// trunc-pack two f32 -> packed bf16 dword (lo=a, hi=b) in ONE v_perm_b32
__device__ __forceinline__ uint32_t pk2(float a, float b) {
    return __builtin_amdgcn_perm(__float_as_uint(b), __float_as_uint(a), 0x07060302);
}

// packed f32 pair multiply: one VOP3P instruction
__device__ __forceinline__ float2 pkmul2(float2 a, float2 b) {
    float2 r;
    asm("v_pk_mul_f32 %0, %1, %2" : "=v"(r) : "v"(a), "v"(b));
    return r;
}

// ---------------------------------------------------------------------------
// Pack W fp32 [s][l][r][w] -> bf16 K-stacked A-operand image, IN PLACE (front
// 16 KB of each 32 KB slab).  Exact r13 form (measured-good).  Separate
// kernel ON PURPOSE: r14/r15 proved in-kernel fusion needs device-scope
// fences that invalidate L2 and cost ~85us; the launch boundary orders
// pack->stage1 while preserving L2-resident images (r13 FETCH=8.5MB).
// ---------------------------------------------------------------------------
__global__ __launch_bounds__(256) void pack_kernel(float* __restrict__ wl,
                                                   float* __restrict__ wr) {
    const int g = blockIdx.x;                 // 0..1023
    const int right = (g >= NSITE) ? 1 : 0;
    const int s = right ? g - NSITE : g;
    float* base = (right ? wr : wl) + (size_t)s * (SLAB_BYTES / 4);

    __shared__ float2 st[DD * 65];            // padded [l][r] (w0,w1) pairs
    const float4* src4 = (const float4*)base; // 16B/lane loads
    for (int e4 = threadIdx.x; e4 < DD * DD / 2; e4 += 256) {
        const float4 v = src4[e4];
        const int e = e4 * 2;                 // e even -> same padded row for e, e+1
        float2* d = &st[(e >> 6) * 65 + (e & 63)];
        d[0] = make_float2(v.x, v.y);
        d[1] = make_float2(v.z, v.w);
    }
    __syncthreads();

    uint32_t* out = (uint32_t*)base;          // front 16 KB = 4096 dwords
    #pragma unroll
    for (int rr = 0; rr < 16; ++rr) {
        const int od = rr * 256 + threadIdx.x;        // coalesced writes
        const int chunk = od >> 8, i = chunk >> 3, sk = chunk & 7;
        const int H = (od >> 7) & 1, m5 = (od >> 2) & 31, d = od & 3;
        const int m = 32 * i + m5, k = 8 * sk + 4 * H + d;
        const float2 a = right ? st[m * 65 + k] : st[k * 65 + m];
        out[od] = pk2(a.x, a.y);              // lo = w0, hi = w1
    }
}

__device__ __forceinline__ void dma16(const void* gp, void* lp) {
    __builtin_amdgcn_global_load_lds(
        (const __attribute__((address_space(1))) uint32_t*)gp,
        (__attribute__((address_space(3))) uint32_t*)lp, 16, 0, 0);
}

// ---------------------------------------------------------------------------
// Stage 1.  Body = r13's proven form (bfa pre-extract, chained acc, XCD
// swizzle).  Occupancy probe: ring 4 -> 3 slots (LDS 66->50 KB) =>
// 3 blocks/CU (12 waves/CU, launch_bounds(256,3)).  3-slot cadence:
//   vmcnt(4) -> s_barrier -> issue site t+2 into slot (t+2)%3 -> compute t.
// Issue AFTER the barrier so the reused slot (all waves read it at t-1,
// before this barrier) is quiescent; vmcnt(4) drains exactly site t's own 4
// chunks, leaving t+1's 4 in flight.  Slots t,t+1,t+2 distinct mod 3.
// Dummy issues at t>=30 land in quiesced slots and are never read.
// af[] preloaded upfront (r6 style, 73.2us vs 74.2 inline).
// ---------------------------------------------------------------------------
__global__ __launch_bounds__(256, 3) void stage1_kernel(
        const float* __restrict__ x, float* __restrict__ wl, float* __restrict__ wr) {
    const int pb   = blockIdx.x;          // physical 0..511
    const int bid  = (pb & 7) * 64 + (pb >> 3);   // logical, XCD-grouped
    const int side = bid >> 8;
    const int seg  = (bid >> 4) & 15;
    const int bq   = bid & 15;
    const int wave = threadIdx.x >> 6;
    const int lane = threadIdx.x & 63;
    const int b    = bq * 4 + wave;
    const int m5   = lane & 31;
    const int H    = lane >> 5;

    __shared__ __align__(16) char ring[3][PACK_BYTES];   // 48 KB
    __shared__ float2 xs[4][SEGLEN];

    char* wbuf = (char*)(side ? wr : wl);

    if (lane < SEGLEN) {
        const float2* xp = ((const float2*)x) + (size_t)b * 1024 + (side ? NSITE : 0);
        const int sg = seg * SEGLEN + (side ? SEGLEN - 1 - lane : lane);
        xs[wave][lane] = xp[sg];
    }

    auto siteAddr = [&](int t) -> const char* {
        const int sg = seg * SEGLEN + (side ? SEGLEN - 1 - t : t);
        return wbuf + (size_t)sg * SLAB_BYTES;
    };

    // prologue: sites 0,1 -> slots 0,1
    #pragma unroll
    for (int t0 = 0; t0 < 2; ++t0) {
        const char* sb = siteAddr(t0);
        #pragma unroll
        for (int c = 0; c < 4; ++c) {
            const int ch = wave * 4 + c;
            dma16(sb + ch * 1024 + lane * 16, ring[t0] + ch * 1024);
        }
    }

    // acc := Identity (C/D layout: row=(q&3)+8(q>>2)+4H, col=32j+m5)
    f32x16 acc[2][2];
    #pragma unroll
    for (int i = 0; i < 2; ++i)
        #pragma unroll
        for (int j = 0; j < 2; ++j)
            #pragma unroll
            for (int q = 0; q < 16; ++q) {
                const int row = (q & 3) + 8 * (q >> 2) + 4 * H;
                acc[i][j][q] = (i == j && row == m5) ? 1.f : 0.f;
            }

    // persistent zero C-operand
    f32x16 zf;
    #pragma unroll
    for (int q = 0; q < 16; ++q) zf[q] = 0.f;

    union BU { bf16x8 v; uint32_t w[4]; };

    int cur = 0;                                   // t % 3, rotating
    for (int t = 0; t < SEGLEN; ++t) {
        asm volatile("s_waitcnt vmcnt(4)" ::: "memory");   // own site-t chunks arrived
        asm volatile("s_barrier" ::: "memory");             // all waves' t data in LDS; slot quiesced

        // issue site t+2 (clamped dummy) into slot (cur+2)%3
        {
            int t2 = t + 2; if (t2 > SEGLEN - 1) t2 = SEGLEN - 1;
            int ns = cur + 2; if (ns >= 3) ns -= 3;
            const char* sb = siteAddr(t2);
            char* lb = ring[ns];
            #pragma unroll
            for (int c = 0; c < 4; ++c) {
                const int ch = wave * 4 + c;
                dma16(sb + ch * 1024 + lane * 16, lb + ch * 1024);
            }
        }

        const char* rb = ring[cur];

        // preload ALL A-fragments (16 x ds_read_b128), r6 style
        uint4 af[2][8];
        #pragma unroll
        for (int i = 0; i < 2; ++i)
            #pragma unroll
            for (int sk = 0; sk < 8; ++sk)
                af[i][sk] = *(const uint4*)(rb + (i * 8 + sk) * 1024 + lane * 16);

        const float2 xv = xs[wave][t];
        const float2 xx = make_float2(xv.x, xv.x);
        const float2 xy = make_float2(xv.y, xv.y);

        // pre-extract ALL B-fragments from acc (reads precede writes; SSA)
        BU bfa[8][2];                              // 64 dwords, static-indexed
        #pragma unroll
        for (int sk = 0; sk < 8; ++sk) {
            const int mi = sk >> 2, qb = 4 * (sk & 3);
            #pragma unroll
            for (int j = 0; j < 2; ++j)
                #pragma unroll
                for (int dp = 0; dp < 2; ++dp) {
                    const float2 v01 = make_float2(acc[mi][j][qb + 2 * dp],
                                                   acc[mi][j][qb + 2 * dp + 1]);
                    const float2 pa = pkmul2(xx, v01);   // {x0*v0, x0*v1}
                    const float2 pb = pkmul2(xy, v01);   // {x1*v0, x1*v1}
                    bfa[sk][j].w[2 * dp + 0] = pk2(pa.x, pb.x);  // kap even: x0
                    bfa[sk][j].w[2 * dp + 1] = pk2(pa.y, pb.y);  // kap odd : x1
                }
        }

        // MFMA cluster: chain directly into acc, C=zf at sk==0
        __builtin_amdgcn_s_setprio(1);
        #pragma unroll
        for (int sk = 0; sk < 8; ++sk) {
            #pragma unroll
            for (int i = 0; i < 2; ++i) {
                union { bf16x8 v; uint4 u; } a; a.u = af[i][sk];
                #pragma unroll
                for (int j = 0; j < 2; ++j)
                    acc[i][j] = __builtin_amdgcn_mfma_f32_32x32x16_bf16(
                        a.v, bfa[sk][j].v, (sk == 0) ? zf : acc[i][j], 0, 0, 0);
            }
        }
        __builtin_amdgcn_s_setprio(0);

        ++cur; if (cur >= 3) cur -= 3;
    }

    // write P (final T, bf16, uint16 index c*64+r) into slab back-halves
    {
        const int p = b * NSEG + seg;                    // 0..1023 per side
        char* pdst = wbuf + (size_t)(p >> 1) * SLAB_BYTES + PACK_BYTES + (p & 1) * 8192;
        #pragma unroll
        for (int i = 0; i < 2; ++i)
            #pragma unroll
            for (int j = 0; j < 2; ++j) {
                const int c = 32 * j + m5;
                #pragma unroll
                for (int Q = 0; Q < 4; ++Q) {
                    const int r0 = 32 * i + 8 * Q + 4 * H;
                    uint2 val;
                    val.x = pk2(acc[i][j][4 * Q + 0], acc[i][j][4 * Q + 1]);
                    val.y = pk2(acc[i][j][4 * Q + 2], acc[i][j][4 * Q + 3]);
                    *(uint2*)(pdst + c * 128 + r0 * 2) = val;
                }
            }
    }
    asm volatile("s_waitcnt vmcnt(0)" ::: "memory");   // drain dummy DMA before endpgm
}

// ---------------------------------------------------------------------------
// FUSED stage2+finalize (r13, measured-good): 64 blocks x 512 threads.
// Waves 0-3 fold LEFT, 4-7 fold RIGHT in parallel; P-prefetch + lgkm-only
// raw barriers; o-parallel contraction at the end.
// ---------------------------------------------------------------------------
__global__ __launch_bounds__(512) void tail_kernel(
        const float* __restrict__ wl, const float* __restrict__ wr,
        const float* __restrict__ core, float* __restrict__ out) {
    const int b    = blockIdx.x;         // 0..63
    const int tid  = threadIdx.x;        // 0..511
    const int side = tid >> 8;           // waves 0-3: left, 4-7: right
    const int r    = tid & 63;
    const int cg   = (tid >> 6) & 3;
    const char* wbuf = (const char*)(side ? wr : wl);

    __shared__ float vsh[2][DD];
    __shared__ float part[2][4][DD];
    if ((tid & 255) < DD) vsh[side][r] = (r == 0) ? 1.f : 0.f;

    auto Pseg = [&](int gi) -> const uint16_t* {
        const int g = side ? (NSEG - 1 - gi) : gi;
        const int p = b * NSEG + g;
        return (const uint16_t*)(wbuf
            + (size_t)(p >> 1) * SLAB_BYTES + PACK_BYTES + (p & 1) * 8192);
    };

    float pv[16];
    {
        const uint16_t* P = Pseg(0);
        #pragma unroll
        for (int cc = 0; cc < 16; ++cc)
            pv[cc] = __uint_as_float(((uint32_t)P[(cg * 16 + cc) * 64 + r]) << 16);
    }
    __syncthreads();

    for (int gi = 0; gi < NSEG; ++gi) {
        float nv[16];
        const bool more = (gi + 1 < NSEG);
        if (more) {
            const uint16_t* Pn = Pseg(gi + 1);          // issue early; waited at copy
            #pragma unroll
            for (int cc = 0; cc < 16; ++cc)
                nv[cc] = __uint_as_float(((uint32_t)Pn[(cg * 16 + cc) * 64 + r]) << 16);
        }
        float acc = 0.f;
        #pragma unroll
        for (int cc = 0; cc < 16; ++cc)
            acc = fmaf(vsh[side][cg * 16 + cc], pv[cc], acc);
        part[side][cg][r] = acc;
        asm volatile("s_waitcnt lgkmcnt(0)" ::: "memory");
        __builtin_amdgcn_s_barrier();
        if ((tid & 255) < DD)
            vsh[side][r] = part[side][0][r] + part[side][1][r]
                         + part[side][2][r] + part[side][3][r];
        asm volatile("s_waitcnt lgkmcnt(0)" ::: "memory");
        __builtin_amdgcn_s_barrier();
        if (more) {
            #pragma unroll
            for (int cc = 0; cc < 16; ++cc) pv[cc] = nv[cc];
        }
    }
    // vsh[0] = vL, vsh[1] = wR.  o-parallel contraction across 8 waves.
    const int wv   = tid >> 6;           // 0..7
    const int lane = tid & 63;
    const float wrv = vsh[1][lane];
    for (int o = wv; o < NO; o += 8) {
        float acc = 0.f;
        #pragma unroll 8
        for (int l = 0; l < DD; ++l)
            acc += vsh[0][l] * core[(o * DD + l) * DD + lane];
        acc *= wrv;
        #pragma unroll
        for (int off = 32; off > 0; off >>= 1)
            acc += __shfl_xor(acc, off, 64);
        if (lane == 0) out[b * NO + o] = acc;
    }
}

extern "C" void kernel_launch(void* const* d_in, const int* in_sizes, int n_in,
                              void* d_out, int out_size, void* d_ws, size_t ws_size,
                              hipStream_t stream) {
    const float* x    = (const float*)d_in[0];   // [64][1024][2]
    float*       wl   = (float*)d_in[1];         // [512][64][64][2] -> packed + P scratch
    const float* core = (const float*)d_in[2];   // [10][64][64]
    float*       wr   = (float*)d_in[3];

    pack_kernel<<<2 * NSITE, 256, 0, stream>>>(wl, wr);
    stage1_kernel<<<512, 256, 0, stream>>>(x, wl, wr);
    tail_kernel<<<NB, 512, 0, stream>>>(wl, wr, core, (float*)d_out);
}

// Round 20
// 162.491 us; speedup vs baseline: 1.5654x; 1.4499x over previous
//
#include <hip/hip_runtime.h>
#include <stdint.h>

#define NSITE 512
#define DD    64
#define NB    64
#define NO    10
#define NSEG  16
#define SEGLEN 32
#define SLAB_BYTES 32768   // fp32 site slab stride
#define PACK_BYTES 16384   // packed bf16 Wstk image (front half of slab)

typedef short bf16x8 __attribute__((ext_vector_type(8)));
typedef float f32x16 __attribute__((ext_vector_type(16)));

// trunc-pack two f32 -> packed bf16 dword (lo=a, hi=b) in ONE v_perm_b32
__device__ __forceinline__ uint32_t pk2(float a, float b) {
    return __builtin_amdgcn_perm(__float_as_uint(b), __float_as_uint(a), 0x07060302);
}

// packed f32 pair multiply: one VOP3P instruction
__device__ __forceinline__ float2 pkmul2(float2 a, float2 b) {
    float2 r;
    asm("v_pk_mul_f32 %0, %1, %2" : "=v"(r) : "v"(a), "v"(b));
    return r;
}

// ---------------------------------------------------------------------------
// Pack W fp32 [s][l][r][w] -> bf16 K-stacked A-operand image, IN PLACE (front
// 16 KB of each 32 KB slab).  Exact r13 form (measured-good).  Separate
// kernel ON PURPOSE: r14/r15 proved in-kernel fusion needs device-scope
// fences that invalidate L2 (~85us); the launch boundary orders pack->stage1
// while preserving L2-resident images (r13 FETCH=8.5MB).
// ---------------------------------------------------------------------------
__global__ __launch_bounds__(256) void pack_kernel(float* __restrict__ wl,
                                                   float* __restrict__ wr) {
    const int g = blockIdx.x;                 // 0..1023
    const int right = (g >= NSITE) ? 1 : 0;
    const int s = right ? g - NSITE : g;
    float* base = (right ? wr : wl) + (size_t)s * (SLAB_BYTES / 4);

    __shared__ float2 st[DD * 65];            // padded [l][r] (w0,w1) pairs
    const float4* src4 = (const float4*)base; // 16B/lane loads
    for (int e4 = threadIdx.x; e4 < DD * DD / 2; e4 += 256) {
        const float4 v = src4[e4];
        const int e = e4 * 2;                 // e even -> same padded row for e, e+1
        float2* d = &st[(e >> 6) * 65 + (e & 63)];
        d[0] = make_float2(v.x, v.y);
        d[1] = make_float2(v.z, v.w);
    }
    __syncthreads();

    uint32_t* out = (uint32_t*)base;          // front 16 KB = 4096 dwords
    #pragma unroll
    for (int rr = 0; rr < 16; ++rr) {
        const int od = rr * 256 + threadIdx.x;        // coalesced writes
        const int chunk = od >> 8, i = chunk >> 3, sk = chunk & 7;
        const int H = (od >> 7) & 1, m5 = (od >> 2) & 31, d = od & 3;
        const int m = 32 * i + m5, k = 8 * sk + 4 * H + d;
        const float2 a = right ? st[m * 65 + k] : st[k * 65 + m];
        out[od] = pk2(a.x, a.y);              // lo = w0, hi = w1
    }
}

__device__ __forceinline__ void dma16(const void* gp, void* lp) {
    __builtin_amdgcn_global_load_lds(
        (const __attribute__((address_space(1))) uint32_t*)gp,
        (__attribute__((address_space(3))) uint32_t*)lp, 16, 0, 0);
}

// ---------------------------------------------------------------------------
// Stage 1.  r19 POST-MORTEM: WRITE_SIZE 269MB (16x) = scratch SPILL -- the
// af[2][8] upfront preload + bfa extraction exceeded the (256,3) cap of
// ~170 VGPR/wave; the occupancy hypothesis was never tested.  THIS ROUND:
// same 3-slot ring + (256,3) + vmcnt(4) cadence, but r13's INLINE A-frag
// reads in the MFMA loop (r13 measured 88 VGPR -> fits the cap, no spill).
// Cadence (audited r16/r17): vmcnt(4) -> s_barrier -> issue t+2 into slot
// (t+2)%3 -> compute t.  Issue after the barrier so the reused slot is
// quiescent; vmcnt(4) drains exactly site t's 4 chunks, t+1 stays in flight.
// ---------------------------------------------------------------------------
__global__ __launch_bounds__(256, 3) void stage1_kernel(
        const float* __restrict__ x, float* __restrict__ wl, float* __restrict__ wr) {
    const int pb   = blockIdx.x;          // physical 0..511
    const int bid  = (pb & 7) * 64 + (pb >> 3);   // logical, XCD-grouped
    const int side = bid >> 8;
    const int seg  = (bid >> 4) & 15;
    const int bq   = bid & 15;
    const int wave = threadIdx.x >> 6;
    const int lane = threadIdx.x & 63;
    const int b    = bq * 4 + wave;
    const int m5   = lane & 31;
    const int H    = lane >> 5;

    __shared__ __align__(16) char ring[3][PACK_BYTES];   // 48 KB
    __shared__ float2 xs[4][SEGLEN];

    char* wbuf = (char*)(side ? wr : wl);

    if (lane < SEGLEN) {
        const float2* xp = ((const float2*)x) + (size_t)b * 1024 + (side ? NSITE : 0);
        const int sg = seg * SEGLEN + (side ? SEGLEN - 1 - lane : lane);
        xs[wave][lane] = xp[sg];
    }

    auto siteAddr = [&](int t) -> const char* {
        const int sg = seg * SEGLEN + (side ? SEGLEN - 1 - t : t);
        return wbuf + (size_t)sg * SLAB_BYTES;
    };

    // prologue: sites 0,1 -> slots 0,1
    #pragma unroll
    for (int t0 = 0; t0 < 2; ++t0) {
        const char* sb = siteAddr(t0);
        #pragma unroll
        for (int c = 0; c < 4; ++c) {
            const int ch = wave * 4 + c;
            dma16(sb + ch * 1024 + lane * 16, ring[t0] + ch * 1024);
        }
    }

    // acc := Identity (C/D layout: row=(q&3)+8(q>>2)+4H, col=32j+m5)
    f32x16 acc[2][2];
    #pragma unroll
    for (int i = 0; i < 2; ++i)
        #pragma unroll
        for (int j = 0; j < 2; ++j)
            #pragma unroll
            for (int q = 0; q < 16; ++q) {
                const int row = (q & 3) + 8 * (q >> 2) + 4 * H;
                acc[i][j][q] = (i == j && row == m5) ? 1.f : 0.f;
            }

    // persistent zero C-operand
    f32x16 zf;
    #pragma unroll
    for (int q = 0; q < 16; ++q) zf[q] = 0.f;

    union BU { bf16x8 v; uint32_t w[4]; };

    int cur = 0;                                   // t % 3, rotating
    for (int t = 0; t < SEGLEN; ++t) {
        asm volatile("s_waitcnt vmcnt(4)" ::: "memory");   // own site-t chunks arrived
        asm volatile("s_barrier" ::: "memory");             // all waves' t data in LDS; slot quiesced

        // issue site t+2 (clamped dummy) into slot (cur+2)%3
        {
            int t2 = t + 2; if (t2 > SEGLEN - 1) t2 = SEGLEN - 1;
            int ns = cur + 2; if (ns >= 3) ns -= 3;
            const char* sb = siteAddr(t2);
            char* lb = ring[ns];
            #pragma unroll
            for (int c = 0; c < 4; ++c) {
                const int ch = wave * 4 + c;
                dma16(sb + ch * 1024 + lane * 16, lb + ch * 1024);
            }
        }

        const char* rb = ring[cur];
        const float2 xv = xs[wave][t];
        const float2 xx = make_float2(xv.x, xv.x);
        const float2 xy = make_float2(xv.y, xv.y);

        // pre-extract ALL B-fragments from acc (reads precede writes; SSA)
        BU bfa[8][2];                              // 64 dwords, static-indexed
        #pragma unroll
        for (int sk = 0; sk < 8; ++sk) {
            const int mi = sk >> 2, qb = 4 * (sk & 3);
            #pragma unroll
            for (int j = 0; j < 2; ++j)
                #pragma unroll
                for (int dp = 0; dp < 2; ++dp) {
                    const float2 v01 = make_float2(acc[mi][j][qb + 2 * dp],
                                                   acc[mi][j][qb + 2 * dp + 1]);
                    const float2 pa = pkmul2(xx, v01);   // {x0*v0, x0*v1}
                    const float2 pb = pkmul2(xy, v01);   // {x1*v0, x1*v1}
                    bfa[sk][j].w[2 * dp + 0] = pk2(pa.x, pb.x);  // kap even: x0
                    bfa[sk][j].w[2 * dp + 1] = pk2(pa.y, pb.y);  // kap odd : x1
                }
        }

        // MFMA cluster: INLINE A-frag reads (r13 form, 88 VGPR), chain into acc
        __builtin_amdgcn_s_setprio(1);
        #pragma unroll
        for (int sk = 0; sk < 8; ++sk) {
            #pragma unroll
            for (int i = 0; i < 2; ++i) {
                union { bf16x8 v; uint4 u; } a;
                a.u = *(const uint4*)(rb + (i * 8 + sk) * 1024 + lane * 16);
                #pragma unroll
                for (int j = 0; j < 2; ++j)
                    acc[i][j] = __builtin_amdgcn_mfma_f32_32x32x16_bf16(
                        a.v, bfa[sk][j].v, (sk == 0) ? zf : acc[i][j], 0, 0, 0);
            }
        }
        __builtin_amdgcn_s_setprio(0);

        ++cur; if (cur >= 3) cur -= 3;
    }

    // write P (final T, bf16, uint16 index c*64+r) into slab back-halves
    {
        const int p = b * NSEG + seg;                    // 0..1023 per side
        char* pdst = wbuf + (size_t)(p >> 1) * SLAB_BYTES + PACK_BYTES + (p & 1) * 8192;
        #pragma unroll
        for (int i = 0; i < 2; ++i)
            #pragma unroll
            for (int j = 0; j < 2; ++j) {
                const int c = 32 * j + m5;
                #pragma unroll
                for (int Q = 0; Q < 4; ++Q) {
                    const int r0 = 32 * i + 8 * Q + 4 * H;
                    uint2 val;
                    val.x = pk2(acc[i][j][4 * Q + 0], acc[i][j][4 * Q + 1]);
                    val.y = pk2(acc[i][j][4 * Q + 2], acc[i][j][4 * Q + 3]);
                    *(uint2*)(pdst + c * 128 + r0 * 2) = val;
                }
            }
    }
    asm volatile("s_waitcnt vmcnt(0)" ::: "memory");   // drain dummy DMA before endpgm
}

// ---------------------------------------------------------------------------
// FUSED stage2+finalize (r13, measured-good): 64 blocks x 512 threads.
// Waves 0-3 fold LEFT, 4-7 fold RIGHT in parallel; P-prefetch + lgkm-only
// raw barriers; o-parallel contraction at the end.
// ---------------------------------------------------------------------------
__global__ __launch_bounds__(512) void tail_kernel(
        const float* __restrict__ wl, const float* __restrict__ wr,
        const float* __restrict__ core, float* __restrict__ out) {
    const int b    = blockIdx.x;         // 0..63
    const int tid  = threadIdx.x;        // 0..511
    const int side = tid >> 8;           // waves 0-3: left, 4-7: right
    const int r    = tid & 63;
    const int cg   = (tid >> 6) & 3;
    const char* wbuf = (const char*)(side ? wr : wl);

    __shared__ float vsh[2][DD];
    __shared__ float part[2][4][DD];
    if ((tid & 255) < DD) vsh[side][r] = (r == 0) ? 1.f : 0.f;

    auto Pseg = [&](int gi) -> const uint16_t* {
        const int g = side ? (NSEG - 1 - gi) : gi;
        const int p = b * NSEG + g;
        return (const uint16_t*)(wbuf
            + (size_t)(p >> 1) * SLAB_BYTES + PACK_BYTES + (p & 1) * 8192);
    };

    float pv[16];
    {
        const uint16_t* P = Pseg(0);
        #pragma unroll
        for (int cc = 0; cc < 16; ++cc)
            pv[cc] = __uint_as_float(((uint32_t)P[(cg * 16 + cc) * 64 + r]) << 16);
    }
    __syncthreads();

    for (int gi = 0; gi < NSEG; ++gi) {
        float nv[16];
        const bool more = (gi + 1 < NSEG);
        if (more) {
            const uint16_t* Pn = Pseg(gi + 1);          // issue early; waited at copy
            #pragma unroll
            for (int cc = 0; cc < 16; ++cc)
                nv[cc] = __uint_as_float(((uint32_t)Pn[(cg * 16 + cc) * 64 + r]) << 16);
        }
        float acc = 0.f;
        #pragma unroll
        for (int cc = 0; cc < 16; ++cc)
            acc = fmaf(vsh[side][cg * 16 + cc], pv[cc], acc);
        part[side][cg][r] = acc;
        asm volatile("s_waitcnt lgkmcnt(0)" ::: "memory");
        __builtin_amdgcn_s_barrier();
        if ((tid & 255) < DD)
            vsh[side][r] = part[side][0][r] + part[side][1][r]
                         + part[side][2][r] + part[side][3][r];
        asm volatile("s_waitcnt lgkmcnt(0)" ::: "memory");
        __builtin_amdgcn_s_barrier();
        if (more) {
            #pragma unroll
            for (int cc = 0; cc < 16; ++cc) pv[cc] = nv[cc];
        }
    }
    // vsh[0] = vL, vsh[1] = wR.  o-parallel contraction across 8 waves.
    const int wv   = tid >> 6;           // 0..7
    const int lane = tid & 63;
    const float wrv = vsh[1][lane];
    for (int o = wv; o < NO; o += 8) {
        float acc = 0.f;
        #pragma unroll 8
        for (int l = 0; l < DD; ++l)
            acc += vsh[0][l] * core[(o * DD + l) * DD + lane];
        acc *= wrv;
        #pragma unroll
        for (int off = 32; off > 0; off >>= 1)
            acc += __shfl_xor(acc, off, 64);
        if (lane == 0) out[b * NO + o] = acc;
    }
}

extern "C" void kernel_launch(void* const* d_in, const int* in_sizes, int n_in,
                              void* d_out, int out_size, void* d_ws, size_t ws_size,
                              hipStream_t stream) {
    const float* x    = (const float*)d_in[0];   // [64][1024][2]
    float*       wl   = (float*)d_in[1];         // [512][64][64][2] -> packed + P scratch
    const float* core = (const float*)d_in[2];   // [10][64][64]
    float*       wr   = (float*)d_in[3];

    pack_kernel<<<2 * NSITE, 256, 0, stream>>>(wl, wr);
    stage1_kernel<<<512, 256, 0, stream>>>(x, wl, wr);
    tail_kernel<<<NB, 512, 0, stream>>>(wl, wr, core, (float*)d_out);
}

// Round 21
// 161.687 us; speedup vs baseline: 1.5732x; 1.0050x over previous
//
#include <hip/hip_runtime.h>
#include <stdint.h>

#define NSITE 512
#define DD    64
#define NB    64
#define NO    10
#define NSEG  16
#define SEGLEN 32
#define SLAB_BYTES 32768   // slab stride: front 16 KB image, back 16 KB P
#define PACK_BYTES 16384
#define WS_NEED (2u * NSITE * SLAB_BYTES)   // 32 MB

typedef short bf16x8 __attribute__((ext_vector_type(8)));
typedef float f32x16 __attribute__((ext_vector_type(16)));

// trunc-pack two f32 -> packed bf16 dword (lo=a, hi=b) in ONE v_perm_b32
__device__ __forceinline__ uint32_t pk2(float a, float b) {
    return __builtin_amdgcn_perm(__float_as_uint(b), __float_as_uint(a), 0x07060302);
}

// packed f32 pair multiply: one VOP3P instruction
__device__ __forceinline__ float2 pkmul2(float2 a, float2 b) {
    float2 r;
    asm("v_pk_mul_f32 %0, %1, %2" : "=v"(r) : "v"(a), "v"(b));
    return r;
}

// ---------------------------------------------------------------------------
// Pack W fp32 [s][l][r][w] -> bf16 K-stacked A-operand image.  r13 body;
// NEW: src and dst may be distinct (dst = d_ws when it fits) so the fp32
// inputs stay PRISTINE -> the harness's per-iteration input-restore
// dispatches (rocprof.md: reset() enqueues them) have nothing to restore.
// Staged through LDS + __syncthreads, so src==dst (fallback) is also safe.
// ---------------------------------------------------------------------------
__global__ __launch_bounds__(256) void pack_kernel(const float* wlsrc,
                                                   const float* wrsrc,
                                                   char* dl, char* dr) {
    const int g = blockIdx.x;                 // 0..1023
    const int right = (g >= NSITE) ? 1 : 0;
    const int s = right ? g - NSITE : g;
    const float* src = (right ? wrsrc : wlsrc) + (size_t)s * (SLAB_BYTES / 4);
    char* dst = (right ? dr : dl) + (size_t)s * SLAB_BYTES;

    __shared__ float2 st[DD * 65];            // padded [l][r] (w0,w1) pairs
    const float4* src4 = (const float4*)src;  // 16B/lane loads
    for (int e4 = threadIdx.x; e4 < DD * DD / 2; e4 += 256) {
        const float4 v = src4[e4];
        const int e = e4 * 2;                 // e even -> same padded row for e, e+1
        float2* d = &st[(e >> 6) * 65 + (e & 63)];
        d[0] = make_float2(v.x, v.y);
        d[1] = make_float2(v.z, v.w);
    }
    __syncthreads();

    uint32_t* out = (uint32_t*)dst;           // front 16 KB = 4096 dwords
    #pragma unroll
    for (int rr = 0; rr < 16; ++rr) {
        const int od = rr * 256 + threadIdx.x;        // coalesced writes
        const int chunk = od >> 8, i = chunk >> 3, sk = chunk & 7;
        const int H = (od >> 7) & 1, m5 = (od >> 2) & 31, d = od & 3;
        const int m = 32 * i + m5, k = 8 * sk + 4 * H + d;
        const float2 a = right ? st[m * 65 + k] : st[k * 65 + m];
        out[od] = pk2(a.x, a.y);              // lo = w0, hi = w1
    }
}

__device__ __forceinline__ void dma16(const void* gp, void* lp) {
    __builtin_amdgcn_global_load_lds(
        (const __attribute__((address_space(1))) uint32_t*)gp,
        (__attribute__((address_space(3))) uint32_t*)lp, 16, 0, 0);
}

// ---------------------------------------------------------------------------
// Stage 1.  FROZEN at the r20 measured form (74.5us, 72 VGPR, no spill):
// 3-slot ring, (256,3), vmcnt(4)+s_barrier cadence, inline A-frag reads,
// bfa pre-extract, chained acc, XCD swizzle.  Five stage1 theories tested
// (VALU r8, dep-latency r10, barrier-count r12, fusion r14/15, occupancy
// r19/20-null-by-grid) -> 2-barrier structure ceiling at ~40% MfmaUtil.
// Only change: operates on dl/dr (images+P region) instead of wl/wr.
// ---------------------------------------------------------------------------
__global__ __launch_bounds__(256, 3) void stage1_kernel(
        const float* __restrict__ x, char* __restrict__ dl, char* __restrict__ dr) {
    const int pb   = blockIdx.x;          // physical 0..511
    const int bid  = (pb & 7) * 64 + (pb >> 3);   // logical, XCD-grouped
    const int side = bid >> 8;
    const int seg  = (bid >> 4) & 15;
    const int bq   = bid & 15;
    const int wave = threadIdx.x >> 6;
    const int lane = threadIdx.x & 63;
    const int b    = bq * 4 + wave;
    const int m5   = lane & 31;
    const int H    = lane >> 5;

    __shared__ __align__(16) char ring[3][PACK_BYTES];   // 48 KB
    __shared__ float2 xs[4][SEGLEN];

    char* wbuf = side ? dr : dl;

    if (lane < SEGLEN) {
        const float2* xp = ((const float2*)x) + (size_t)b * 1024 + (side ? NSITE : 0);
        const int sg = seg * SEGLEN + (side ? SEGLEN - 1 - lane : lane);
        xs[wave][lane] = xp[sg];
    }

    auto siteAddr = [&](int t) -> const char* {
        const int sg = seg * SEGLEN + (side ? SEGLEN - 1 - t : t);
        return wbuf + (size_t)sg * SLAB_BYTES;
    };

    // prologue: sites 0,1 -> slots 0,1
    #pragma unroll
    for (int t0 = 0; t0 < 2; ++t0) {
        const char* sb = siteAddr(t0);
        #pragma unroll
        for (int c = 0; c < 4; ++c) {
            const int ch = wave * 4 + c;
            dma16(sb + ch * 1024 + lane * 16, ring[t0] + ch * 1024);
        }
    }

    // acc := Identity (C/D layout: row=(q&3)+8(q>>2)+4H, col=32j+m5)
    f32x16 acc[2][2];
    #pragma unroll
    for (int i = 0; i < 2; ++i)
        #pragma unroll
        for (int j = 0; j < 2; ++j)
            #pragma unroll
            for (int q = 0; q < 16; ++q) {
                const int row = (q & 3) + 8 * (q >> 2) + 4 * H;
                acc[i][j][q] = (i == j && row == m5) ? 1.f : 0.f;
            }

    // persistent zero C-operand
    f32x16 zf;
    #pragma unroll
    for (int q = 0; q < 16; ++q) zf[q] = 0.f;

    union BU { bf16x8 v; uint32_t w[4]; };

    int cur = 0;                                   // t % 3, rotating
    for (int t = 0; t < SEGLEN; ++t) {
        asm volatile("s_waitcnt vmcnt(4)" ::: "memory");   // own site-t chunks arrived
        asm volatile("s_barrier" ::: "memory");             // all waves' t data in LDS; slot quiesced

        // issue site t+2 (clamped dummy) into slot (cur+2)%3
        {
            int t2 = t + 2; if (t2 > SEGLEN - 1) t2 = SEGLEN - 1;
            int ns = cur + 2; if (ns >= 3) ns -= 3;
            const char* sb = siteAddr(t2);
            char* lb = ring[ns];
            #pragma unroll
            for (int c = 0; c < 4; ++c) {
                const int ch = wave * 4 + c;
                dma16(sb + ch * 1024 + lane * 16, lb + ch * 1024);
            }
        }

        const char* rb = ring[cur];
        const float2 xv = xs[wave][t];
        const float2 xx = make_float2(xv.x, xv.x);
        const float2 xy = make_float2(xv.y, xv.y);

        // pre-extract ALL B-fragments from acc (reads precede writes; SSA)
        BU bfa[8][2];                              // 64 dwords, static-indexed
        #pragma unroll
        for (int sk = 0; sk < 8; ++sk) {
            const int mi = sk >> 2, qb = 4 * (sk & 3);
            #pragma unroll
            for (int j = 0; j < 2; ++j)
                #pragma unroll
                for (int dp = 0; dp < 2; ++dp) {
                    const float2 v01 = make_float2(acc[mi][j][qb + 2 * dp],
                                                   acc[mi][j][qb + 2 * dp + 1]);
                    const float2 pa = pkmul2(xx, v01);   // {x0*v0, x0*v1}
                    const float2 pb = pkmul2(xy, v01);   // {x1*v0, x1*v1}
                    bfa[sk][j].w[2 * dp + 0] = pk2(pa.x, pb.x);  // kap even: x0
                    bfa[sk][j].w[2 * dp + 1] = pk2(pa.y, pb.y);  // kap odd : x1
                }
        }

        // MFMA cluster: inline A-frag reads (72 VGPR, no spill), chain into acc
        __builtin_amdgcn_s_setprio(1);
        #pragma unroll
        for (int sk = 0; sk < 8; ++sk) {
            #pragma unroll
            for (int i = 0; i < 2; ++i) {
                union { bf16x8 v; uint4 u; } a;
                a.u = *(const uint4*)(rb + (i * 8 + sk) * 1024 + lane * 16);
                #pragma unroll
                for (int j = 0; j < 2; ++j)
                    acc[i][j] = __builtin_amdgcn_mfma_f32_32x32x16_bf16(
                        a.v, bfa[sk][j].v, (sk == 0) ? zf : acc[i][j], 0, 0, 0);
            }
        }
        __builtin_amdgcn_s_setprio(0);

        ++cur; if (cur >= 3) cur -= 3;
    }

    // write P (final T, bf16, uint16 index c*64+r) into slab back-halves
    {
        const int p = b * NSEG + seg;                    // 0..1023 per side
        char* pdst = wbuf + (size_t)(p >> 1) * SLAB_BYTES + PACK_BYTES + (p & 1) * 8192;
        #pragma unroll
        for (int i = 0; i < 2; ++i)
            #pragma unroll
            for (int j = 0; j < 2; ++j) {
                const int c = 32 * j + m5;
                #pragma unroll
                for (int Q = 0; Q < 4; ++Q) {
                    const int r0 = 32 * i + 8 * Q + 4 * H;
                    uint2 val;
                    val.x = pk2(acc[i][j][4 * Q + 0], acc[i][j][4 * Q + 1]);
                    val.y = pk2(acc[i][j][4 * Q + 2], acc[i][j][4 * Q + 3]);
                    *(uint2*)(pdst + c * 128 + r0 * 2) = val;
                }
            }
    }
    asm volatile("s_waitcnt vmcnt(0)" ::: "memory");   // drain dummy DMA before endpgm
}

// ---------------------------------------------------------------------------
// FUSED stage2+finalize (r13, measured-good): 64 blocks x 512 threads.
// Waves 0-3 fold LEFT, 4-7 fold RIGHT in parallel; P-prefetch + lgkm-only
// raw barriers; o-parallel contraction at the end.  Reads P from dl/dr.
// ---------------------------------------------------------------------------
__global__ __launch_bounds__(512) void tail_kernel(
        const char* __restrict__ dl, const char* __restrict__ dr,
        const float* __restrict__ core, float* __restrict__ out) {
    const int b    = blockIdx.x;         // 0..63
    const int tid  = threadIdx.x;        // 0..511
    const int side = tid >> 8;           // waves 0-3: left, 4-7: right
    const int r    = tid & 63;
    const int cg   = (tid >> 6) & 3;
    const char* wbuf = side ? dr : dl;

    __shared__ float vsh[2][DD];
    __shared__ float part[2][4][DD];
    if ((tid & 255) < DD) vsh[side][r] = (r == 0) ? 1.f : 0.f;

    auto Pseg = [&](int gi) -> const uint16_t* {
        const int g = side ? (NSEG - 1 - gi) : gi;
        const int p = b * NSEG + g;
        return (const uint16_t*)(wbuf
            + (size_t)(p >> 1) * SLAB_BYTES + PACK_BYTES + (p & 1) * 8192);
    };

    float pv[16];
    {
        const uint16_t* P = Pseg(0);
        #pragma unroll
        for (int cc = 0; cc < 16; ++cc)
            pv[cc] = __uint_as_float(((uint32_t)P[(cg * 16 + cc) * 64 + r]) << 16);
    }
    __syncthreads();

    for (int gi = 0; gi < NSEG; ++gi) {
        float nv[16];
        const bool more = (gi + 1 < NSEG);
        if (more) {
            const uint16_t* Pn = Pseg(gi + 1);          // issue early; waited at copy
            #pragma unroll
            for (int cc = 0; cc < 16; ++cc)
                nv[cc] = __uint_as_float(((uint32_t)Pn[(cg * 16 + cc) * 64 + r]) << 16);
        }
        float acc = 0.f;
        #pragma unroll
        for (int cc = 0; cc < 16; ++cc)
            acc = fmaf(vsh[side][cg * 16 + cc], pv[cc], acc);
        part[side][cg][r] = acc;
        asm volatile("s_waitcnt lgkmcnt(0)" ::: "memory");
        __builtin_amdgcn_s_barrier();
        if ((tid & 255) < DD)
            vsh[side][r] = part[side][0][r] + part[side][1][r]
                         + part[side][2][r] + part[side][3][r];
        asm volatile("s_waitcnt lgkmcnt(0)" ::: "memory");
        __builtin_amdgcn_s_barrier();
        if (more) {
            #pragma unroll
            for (int cc = 0; cc < 16; ++cc) pv[cc] = nv[cc];
        }
    }
    // vsh[0] = vL, vsh[1] = wR.  o-parallel contraction across 8 waves.
    const int wv   = tid >> 6;           // 0..7
    const int lane = tid & 63;
    const float wrv = vsh[1][lane];
    for (int o = wv; o < NO; o += 8) {
        float acc = 0.f;
        #pragma unroll 8
        for (int l = 0; l < DD; ++l)
            acc += vsh[0][l] * core[(o * DD + l) * DD + lane];
        acc *= wrv;
        #pragma unroll
        for (int off = 32; off > 0; off >>= 1)
            acc += __shfl_xor(acc, off, 64);
        if (lane == 0) out[b * NO + o] = acc;
    }
}

extern "C" void kernel_launch(void* const* d_in, const int* in_sizes, int n_in,
                              void* d_out, int out_size, void* d_ws, size_t ws_size,
                              hipStream_t stream) {
    const float* x    = (const float*)d_in[0];   // [64][1024][2]
    float*       wl   = (float*)d_in[1];         // [512][64][64][2] fp32
    const float* core = (const float*)d_in[2];   // [10][64][64]
    float*       wr   = (float*)d_in[3];

    char* dl;
    char* dr;
    if (ws_size >= (size_t)WS_NEED) {   // keep inputs pristine -> no restores
        dl = (char*)d_ws;
        dr = dl + (size_t)NSITE * SLAB_BYTES;
    } else {                             // fallback: in-place (r20 behavior)
        dl = (char*)wl;
        dr = (char*)wr;
    }

    pack_kernel<<<2 * NSITE, 256, 0, stream>>>(wl, wr, dl, dr);
    stage1_kernel<<<512, 256, 0, stream>>>(x, dl, dr);
    tail_kernel<<<NB, 512, 0, stream>>>(dl, dr, core, (float*)d_out);
}